// Round 11
// baseline (646.935 us; speedup 1.0000x reference)
//
#include <hip/hip_runtime.h>
#include <math.h>

#define BB 64
#define TT 2048
#define FF 128
#define HH 32
#define GG 128   // 4*H
#define CH 64    // timesteps per producer/consumer chunk
#define NCH (TT / CH)

// gate-column prescale: sigma(a) = rcp(1 + exp2(S1*a)), tanh(a) = 2*rcp(1+exp2(S2*a))-1
#define S1f (-1.4426950408889634f)  // -log2(e)
#define S2f (-2.8853900817779268f)  // -2*log2(e)

typedef _Float16 half2_t __attribute__((ext_vector_type(2)));

__device__ __forceinline__ unsigned h2u(half2_t v) {
    unsigned u; __builtin_memcpy(&u, &v, 4); return u;
}
__device__ __forceinline__ half2_t u2h(unsigned u) {
    half2_t v; __builtin_memcpy(&v, &u, 4); return v;
}
__device__ __forceinline__ half2_t pkrtz(float a, float b) {
    auto r = __builtin_amdgcn_cvt_pkrtz(a, b);  // __fp16 vec2, same bits
    half2_t v; __builtin_memcpy(&v, &r, 4); return v;
}
__device__ __forceinline__ float rcp_(float x) { return __builtin_amdgcn_rcpf(x); }
__device__ __forceinline__ float exp2_(float x) { return __builtin_amdgcn_exp2f(x); }
__device__ __forceinline__ float fdot2_(half2_t a, half2_t b, float c) {
    return __builtin_amdgcn_fdot2(a, b, c, false);
}

// DPP lane shuffles (within rows of 16 / quads); bound_ctrl=1, all rows/banks
#define DPP_(x, ctrl) \
    ((unsigned)__builtin_amdgcn_mov_dpp((int)(x), (ctrl), 0xF, 0xF, true))
#define CTRL_XOR1 0xB1  // quad_perm [1,0,3,2]
#define CTRL_XOR2 0x4E  // quad_perm [2,3,0,1]
#define CTRL_ROR4 0x124 // row_ror:4
#define CTRL_ROR8 0x128 // row_ror:8
// ds_swizzle bit-mode xor16 within 32-lane groups: (16<<10)|0x1F
#define SWZ16_(x) ((unsigned)__builtin_amdgcn_ds_swizzle((int)(x), 0x401F))

#if __has_builtin(__builtin_amdgcn_permlane16_swap)
#define HAVE_PL16 1
#else
#define HAVE_PL16 0
#endif

// 16-reg all-gather tree from seed reg v0 (packed pair or index). All ops stay
// within 32-lane groups. The same tree runs on indices at setup (discovery)
// and on h each step, so only the permutation's fixedness matters.
__device__ __forceinline__ void gather_tree(unsigned v0, unsigned g[16]) {
    unsigned v1 = DPP_(v0, CTRL_XOR2);
#if HAVE_PL16
    auto sw = __builtin_amdgcn_permlane16_swap(v0, v1, false, false);
    unsigned s0 = (unsigned)sw[0], s1 = (unsigned)sw[1];
    g[0] = s0;
    g[1] = s1;
    g[2] = DPP_(s0, CTRL_XOR2);
    g[3] = DPP_(s1, CTRL_XOR2);
#else
    g[0] = v0;
    g[1] = v1;
    g[2] = SWZ16_(v0);
    g[3] = SWZ16_(v1);
#endif
#pragma unroll
    for (int r = 0; r < 4; ++r) g[4 + r] = DPP_(g[r], CTRL_ROR4);
#pragma unroll
    for (int r = 0; r < 8; ++r) g[8 + r] = DPP_(g[r], CTRL_ROR8);
}

// ---------------- Fused kernel: one block per batch element ----------------
// 256 threads = 4 waves. Wave 0: sequential LSTM scan (round-8 structure:
// lane l owns gate cols l and l+64; all-VALU h-gather; permlane32 gate
// exchange). Waves 1-3: producers computing xg preacts for chunk k+1 via
// fp16 fdot2 against LDS-staged packed Wx while wave 0 scans chunk k.
// Double-buffered LDS xg; one __syncthreads per chunk.
__global__ __launch_bounds__(256) void lstm_fused(const float* __restrict__ X,
                                                  const float* __restrict__ Wx,
                                                  const float* __restrict__ Wh,
                                                  const float* __restrict__ bias,
                                                  const float* __restrict__ Wd,
                                                  const float* __restrict__ bd,
                                                  float* __restrict__ out) {
    __shared__ unsigned xbuf[2][CH][64];  // 32 KB: [buf][t][scan-lane] packed fp16 pair
    __shared__ uint4 wxl[64][32];         // 32 KB: [k-pair r][m] -> 4 gate half2

    const int tid = threadIdx.x;
    const int wid = tid >> 6;
    const int l   = tid & 63;
    const int m32 = l & 31;
    const bool lo = (l < HH);
    const int b   = blockIdx.x;

    // ---- one-time: stage packed Wx into LDS (all 256 threads) ----
    // wxl[r][m] = (pk(Wx[2r][m],Wx[2r+1][m]), pk(..m+32..), pk(..m+64), pk(..m+96))
#pragma unroll
    for (int j = 0; j < 8; ++j) {
        int idx = tid + j * 256;          // 0..2047
        int r = idx >> 5, m = idx & 31;
        const float* w0 = Wx + (size_t)(2 * r) * GG + m;
        const float* w1 = w0 + GG;
        uint4 e;
        e.x = h2u(pkrtz(w0[0],  w1[0]));
        e.y = h2u(pkrtz(w0[32], w1[32]));
        e.z = h2u(pkrtz(w0[64], w1[64]));
        e.w = h2u(pkrtz(w0[96], w1[96]));
        wxl[r][m] = e;
    }
    // (visible to producers after the k=0 __syncthreads below)

    // ---- scanner state (wave 0 only) ----
    float h = 0.f, c = 0.f;
    half2_t whx[16], why[16];
    float A1 = 1.f, B1 = 0.f;
    // ---- producer state (waves 1-3) ----
    float bI = 0.f, bF = 0.f, bG = 0.f, bO = 0.f;
    const int dtp = l >> 5;

    if (wid == 0) {
        unsigned iv[16];
        gather_tree((unsigned)m32, iv);
        const float scx = S1f;                 // col l: i (lo) or f (hi)
        const float scy = lo ? S2f : S1f;      // col l+64: g (lo) or o (hi)
#pragma unroll
        for (int r = 0; r < 16; ++r) {
            const int p  = (int)(iv[r] & 31u);
            const int p2 = p ^ 1;
            whx[r] = pkrtz(Wh[p * GG + l] * scx,      Wh[p2 * GG + l] * scx);
            why[r] = pkrtz(Wh[p * GG + l + 64] * scy, Wh[p2 * GG + l + 64] * scy);
        }
        A1 = lo ? 2.f : 1.f;
        B1 = lo ? -1.f : 0.f;
    } else {
        bI = bias[m32];
        bF = bias[m32 + 32];
        bG = bias[m32 + 64];
        bO = bias[m32 + 96];
    }

    auto step = [&](unsigned w) __attribute__((always_inline)) {
        half2_t xv = u2h(w);
        float xi = (float)xv[0];   // prescaled preact, col l   (i|f)
        float xy = (float)xv[1];   // prescaled preact, col l+64 (g|o)
        // all-VALU butterfly gather: h -> 16 packed half2
        unsigned hn = DPP_(__float_as_uint(h), CTRL_XOR1);
        unsigned g0 = h2u(pkrtz(h, __uint_as_float(hn)));
        unsigned g[16];
        gather_tree(g0, g);
        // matvec: 32 all-VGPR fdot2, 4-way split accumulators
        float ax[4] = {xi, 0.f, 0.f, 0.f};
        float ay[4] = {xy, 0.f, 0.f, 0.f};
#pragma unroll
        for (int r = 0; r < 16; ++r) {
            half2_t hp = u2h(g[r]);
            ax[r & 3] = fdot2_(hp, whx[r], ax[r & 3]);
            ay[r & 3] = fdot2_(hp, why[r], ay[r & 3]);
        }
        float a0 = (ax[0] + ax[1]) + (ax[2] + ax[3]);
        float a1 = (ay[0] + ay[1]) + (ay[2] + ay[3]);
        // act0 = sigmoid (i|f); act1 = tanh (g) on lo, sigmoid (o) on hi
        float act0 = rcp_(1.f + exp2_(a0));
        float act1 = fmaf(A1, rcp_(1.f + exp2_(a1)), B1);
        // two independent half-swaps: p={i|g} q={f|o} u={g|i} v={o|f}
        auto pq = __builtin_amdgcn_permlane32_swap(__float_as_uint(act0),
                                                   __float_as_uint(act1), false, false);
        auto uv = __builtin_amdgcn_permlane32_swap(__float_as_uint(act1),
                                                   __float_as_uint(act0), false, false);
        float p = __uint_as_float(pq[0]);
        float q = __uint_as_float(pq[1]);
        float u = __uint_as_float(uv[0]);
        float v = __uint_as_float(uv[1]);
        float f_all = lo ? q : act0;   // sigmoid(f)
        float o_all = lo ? v : act1;   // sigmoid(o)
        c = fmaf(f_all, c, u * p);     // u*p = i*g in every lane
        float tc = fmaf(2.f, rcp_(1.f + exp2_(c * S2f)), -1.f);  // tanh(c)
        h = o_all * tc;
    };

    // ---- main producer/consumer loop: one barrier per chunk ----
    for (int k = 0; k <= NCH; ++k) {
        __syncthreads();
        if (wid == 0) {
            if (k == 0) continue;     // nothing to consume yet
            const unsigned* col = &xbuf[(k - 1) & 1][0][l];
            unsigned c0 = col[0], c1 = col[64], c2 = col[128], c3 = col[192];
#pragma unroll 1
            for (int g4 = 0; g4 < CH; g4 += 4) {
                unsigned n0 = 0, n1 = 0, n2 = 0, n3 = 0;
                if (g4 + 4 < CH) {
                    const unsigned* nc = col + (g4 + 4) * 64;
                    n0 = nc[0]; n1 = nc[64]; n2 = nc[128]; n3 = nc[192];
                }
                step(c0); step(c1); step(c2); step(c3);
                c0 = n0; c1 = n1; c2 = n2; c3 = n3;
            }
        } else if (k < NCH) {
            const int t0 = k * CH;
            unsigned (*ob)[64] = xbuf[k & 1];
            // waves 1-3 x dt halves cover offsets 0..5 (stride 6) within the chunk
            for (int tt = t0 + (wid - 1) * 2 + dtp; tt < t0 + CH; tt += 6) {
                const float4* xr = (const float4*)(X + ((size_t)b * TT + tt) * FF);
                float aI = bI, aF = bF, aG = bG, aO = bO;
#pragma unroll 4
                for (int kk = 0; kk < 16; ++kk) {
                    float4 xa = xr[2 * kk];
                    float4 xb = xr[2 * kk + 1];
                    half2_t p0 = pkrtz(xa.x, xa.y);
                    half2_t p1 = pkrtz(xa.z, xa.w);
                    half2_t p2 = pkrtz(xb.x, xb.y);
                    half2_t p3 = pkrtz(xb.z, xb.w);
                    uint4 w0 = wxl[4 * kk + 0][m32];
                    uint4 w1 = wxl[4 * kk + 1][m32];
                    uint4 w2 = wxl[4 * kk + 2][m32];
                    uint4 w3 = wxl[4 * kk + 3][m32];
                    aI = fdot2_(p0, u2h(w0.x), aI); aF = fdot2_(p0, u2h(w0.y), aF);
                    aG = fdot2_(p0, u2h(w0.z), aG); aO = fdot2_(p0, u2h(w0.w), aO);
                    aI = fdot2_(p1, u2h(w1.x), aI); aF = fdot2_(p1, u2h(w1.y), aF);
                    aG = fdot2_(p1, u2h(w1.z), aG); aO = fdot2_(p1, u2h(w1.w), aO);
                    aI = fdot2_(p2, u2h(w2.x), aI); aF = fdot2_(p2, u2h(w2.y), aF);
                    aG = fdot2_(p2, u2h(w2.z), aG); aO = fdot2_(p2, u2h(w2.w), aO);
                    aI = fdot2_(p3, u2h(w3.x), aI); aF = fdot2_(p3, u2h(w3.y), aF);
                    aG = fdot2_(p3, u2h(w3.z), aG); aO = fdot2_(p3, u2h(w3.w), aO);
                }
                // scanner lane l<32 reads (i', g'); lane l>=32 reads (f', o')
                ob[tt - t0][m32]      = h2u(pkrtz(aI * S1f, aG * S2f));
                ob[tt - t0][m32 + 32] = h2u(pkrtz(aF * S1f, aO * S1f));
            }
        }
    }

    // ---- epilogue: out[b] = h_T @ Wd + bd (h duplicated across halves) ----
    if (wid == 0) {
        float ca = h * Wd[m32];
#pragma unroll
        for (int off = 32; off >= 1; off >>= 1)
            ca += __shfl_xor(ca, off, 64);
        if (l == 0) out[b] = fmaf(0.5f, ca, bd[0]);
    }
}

extern "C" void kernel_launch(void* const* d_in, const int* in_sizes, int n_in,
                              void* d_out, int out_size, void* d_ws, size_t ws_size,
                              hipStream_t stream) {
    const float* X    = (const float*)d_in[0];
    const float* Wx   = (const float*)d_in[1];
    const float* Wh   = (const float*)d_in[2];
    const float* bias = (const float*)d_in[3];
    const float* Wd   = (const float*)d_in[4];
    const float* bd   = (const float*)d_in[5];
    float* out = (float*)d_out;

    hipLaunchKernelGGL(lstm_fused, dim3(BB), dim3(256), 0, stream,
                       X, Wx, Wh, bias, Wd, bd, out);
}